// Round 3
// baseline (204.671 us; speedup 1.0000x reference)
//
#include <hip/hip_runtime.h>

typedef __attribute__((ext_vector_type(8))) short short8v;
typedef __attribute__((ext_vector_type(4))) float f32x4;

#define BATCH 128
#define CIN 8
#define HW 128
#define COUT 64
#define OHW 126
#define PH 31
#define GN_EPS 1e-5f

#define ROWS_A 8
#define STRIPS_A 16
#define INROWS_A 11   // 10 real (clipped) + 1 zero row
#define INROWS_B 7    // 6 real + 1 zero row
#define ACOLS 132

static __device__ __forceinline__ unsigned short f2bf(float f) {
    unsigned u = __float_as_uint(f);
    return (unsigned short)((u + 0x7fffu + ((u >> 16) & 1u)) >> 16);
}
static __device__ __forceinline__ unsigned pk2(float a, float b) {
    return (unsigned)f2bf(a) | ((unsigned)f2bf(b) << 16);
}

// ---- prep: pack weights into MFMA B-fragment order, bf16 ----
// Bpack[((dx*4+nt)*64+lane)*8 + j] = w[nt*16+(lane&15)][cin=j][dy=lane>>4][dx], 0 for dy==3
__global__ __launch_bounds__(256) void prep_weights(const float* __restrict__ w,
                                                    short* __restrict__ Bpack)
{
    for (int e = threadIdx.x; e < 3 * 4 * 64; e += 256) {
        int dx = e >> 8;
        int nt = (e >> 6) & 3;
        int l  = e & 63;
        int i = l & 15, g = l >> 4;
        int n = nt * 16 + i;
        #pragma unroll
        for (int j = 0; j < 8; ++j) {
            float v = (g < 3) ? w[((n * CIN + j) * 3 + g) * 3 + dx] : 0.f;
            Bpack[e * 8 + j] = (short)f2bf(v);
        }
    }
}

// ---- pass A: bf16-MFMA conv (no bias) + per-(b,channel) partial stats ----
__global__ __launch_bounds__(256, 4) void conv_stats(
    const float* __restrict__ x, const short* __restrict__ Bpack,
    float* __restrict__ part)
{
    __shared__ __align__(16) short Abuf[INROWS_A][ACOLS][8];
    __shared__ float red[4][COUT][2];
    const int strip = blockIdx.x, b = blockIdx.y;
    const int tid = threadIdx.x, wave = tid >> 6, lane = tid & 63;
    const int i = lane & 15, g = lane >> 4;
    const int r0 = strip * ROWS_A;

    // stage: 4 entries per thread via float4-per-cin loads
    {
        const float* xb = x + (size_t)b * CIN * HW * HW;
        for (int e = tid; e < INROWS_A * 33; e += 256) {
            int row = e / 33, cg = e % 33;
            int col0 = cg << 2;
            int ri = r0 + row;
            float4 v[8];
            if (row < 10 && ri < HW && cg < 32) {
                #pragma unroll
                for (int ci = 0; ci < 8; ++ci)
                    v[ci] = *(const float4*)&xb[((size_t)ci * HW + ri) * HW + col0];
            } else {
                #pragma unroll
                for (int ci = 0; ci < 8; ++ci) v[ci] = make_float4(0.f, 0.f, 0.f, 0.f);
            }
            const float* vf = (const float*)v;
            #pragma unroll
            for (int j = 0; j < 4; ++j) {
                uint4 u;
                u.x = pk2(vf[0 * 4 + j], vf[1 * 4 + j]);
                u.y = pk2(vf[2 * 4 + j], vf[3 * 4 + j]);
                u.z = pk2(vf[4 * 4 + j], vf[5 * 4 + j]);
                u.w = pk2(vf[6 * 4 + j], vf[7 * 4 + j]);
                *(uint4*)&Abuf[row][col0 + j][0] = u;
            }
        }
    }

    // B fragments (12 x 16B)
    short8v bq[3][4];
    {
        const uint4* bp = (const uint4*)Bpack;
        #pragma unroll
        for (int dx = 0; dx < 3; ++dx)
            #pragma unroll
            for (int nt = 0; nt < 4; ++nt) {
                uint4 t4 = bp[(dx * 4 + nt) * 64 + lane];
                bq[dx][nt] = *(short8v*)&t4;
            }
    }
    __syncthreads();

    float s1[4] = {0.f, 0.f, 0.f, 0.f}, s2[4] = {0.f, 0.f, 0.f, 0.f};
    const short* zp = &Abuf[INROWS_A - 1][0][0];
    #pragma unroll
    for (int rr = 0; rr < 2; ++rr) {
        const int rloc = wave + rr * 4;
        if (r0 + rloc < OHW) {
            for (int t = 0; t < 8; ++t) {
                f32x4 acc[4];
                #pragma unroll
                for (int nt = 0; nt < 4; ++nt) acc[nt] = (f32x4){0.f, 0.f, 0.f, 0.f};
                #pragma unroll
                for (int dx = 0; dx < 3; ++dx) {
                    const short* ap = &Abuf[rloc + g][16 * t + i + dx][0];
                    if (t == 7 && i >= 14) ap = zp;  // mask cols 126,127 -> C rows = 0
                    short8v a = *(const short8v*)ap;
                    #pragma unroll
                    for (int nt = 0; nt < 4; ++nt)
                        acc[nt] = __builtin_amdgcn_mfma_f32_16x16x32_bf16(a, bq[dx][nt], acc[nt], 0, 0, 0);
                }
                #pragma unroll
                for (int nt = 0; nt < 4; ++nt)
                    #pragma unroll
                    for (int r = 0; r < 4; ++r) {
                        float vv = acc[nt][r];
                        s1[nt] += vv;
                        s2[nt] = fmaf(vv, vv, s2[nt]);
                    }
            }
        }
    }

    // sum over m-rows (g) only; keep per-channel
    #pragma unroll
    for (int nt = 0; nt < 4; ++nt) {
        s1[nt] += __shfl_xor(s1[nt], 16); s1[nt] += __shfl_xor(s1[nt], 32);
        s2[nt] += __shfl_xor(s2[nt], 16); s2[nt] += __shfl_xor(s2[nt], 32);
    }
    if (g == 0) {
        #pragma unroll
        for (int nt = 0; nt < 4; ++nt) {
            red[wave][nt * 16 + i][0] = s1[nt];
            red[wave][nt * 16 + i][1] = s2[nt];
        }
    }
    __syncthreads();
    if (tid < 128) {
        int c = tid >> 1, w = tid & 1;
        float v = red[0][c][w] + red[1][c][w] + red[2][c][w] + red[3][c][w];
        part[(((size_t)b * STRIPS_A + strip) * COUT + c) * 2 + w] = v;
    }
}

// ---- fold stats + bias into per-(b,c) affine A, B2 ----
__global__ __launch_bounds__(256) void finalize_stats(
    const float* __restrict__ part, const float* __restrict__ gnw,
    const float* __restrict__ gnb, const float* __restrict__ scale,
    const float* __restrict__ bias, float* __restrict__ Aarr, float* __restrict__ B2arr)
{
    int t = blockIdx.x * 256 + threadIdx.x;  // 8192 = 128 b * 64 c
    int b = t >> 6, c = t & 63;
    float s1 = 0.f, s2 = 0.f;
    for (int s = 0; s < STRIPS_A; ++s) {
        const float* p = &part[(((size_t)b * STRIPS_A + s) * COUT + c) * 2];
        s1 += p[0]; s2 += p[1];
    }
    const float Nf = (float)(OHW * OHW);
    float bc = bias[c];
    float S2 = s2 + 2.f * bc * s1 + Nf * bc * bc;  // sum (y_raw+b)^2
    float S1 = s1 + Nf * bc;                        // sum (y_raw+b)
    // group sums (4 adjacent channels, same wave)
    float G1 = S1 + __shfl_xor(S1, 1); G1 += __shfl_xor(G1, 2);
    float G2 = S2 + __shfl_xor(S2, 1); G2 += __shfl_xor(G2, 2);
    float invN = 1.f / (4.f * Nf);
    float mean = G1 * invN;
    float var = G2 * invN - mean * mean;
    float rstd = rsqrtf(var + GN_EPS);
    float A = rstd * gnw[c] * scale[c];
    float B2 = (gnb[c] - mean * rstd * gnw[c]) * scale[c] + bc * A;
    Aarr[t] = A;
    B2arr[t] = B2;
}

// ---- pass B: bf16-MFMA conv + affine + in-register maxpool + clamp ----
__global__ __launch_bounds__(256, 4) void conv_pool(
    const float* __restrict__ x, const short* __restrict__ Bpack,
    const float* __restrict__ Aarr, const float* __restrict__ B2arr,
    float* __restrict__ out)
{
    __shared__ __align__(16) short Abuf[INROWS_B][ACOLS][8];
    const int prow = blockIdx.x, b = blockIdx.y;
    const int tid = threadIdx.x, wave = tid >> 6, lane = tid & 63;
    const int i = lane & 15, g = lane >> 4;
    const int r0 = prow * 4;

    // stage 7 rows x 33 col-groups = 231 entries, one per thread
    {
        const float* xb = x + (size_t)b * CIN * HW * HW;
        if (tid < INROWS_B * 33) {
            int row = tid / 33, cg = tid % 33;
            int col0 = cg << 2;
            int ri = r0 + row;
            float4 v[8];
            if (row < 6 && cg < 32) {
                #pragma unroll
                for (int ci = 0; ci < 8; ++ci)
                    v[ci] = *(const float4*)&xb[((size_t)ci * HW + ri) * HW + col0];
            } else {
                #pragma unroll
                for (int ci = 0; ci < 8; ++ci) v[ci] = make_float4(0.f, 0.f, 0.f, 0.f);
            }
            const float* vf = (const float*)v;
            #pragma unroll
            for (int j = 0; j < 4; ++j) {
                uint4 u;
                u.x = pk2(vf[0 * 4 + j], vf[1 * 4 + j]);
                u.y = pk2(vf[2 * 4 + j], vf[3 * 4 + j]);
                u.z = pk2(vf[4 * 4 + j], vf[5 * 4 + j]);
                u.w = pk2(vf[6 * 4 + j], vf[7 * 4 + j]);
                *(uint4*)&Abuf[row][col0 + j][0] = u;
            }
        }
    }

    short8v bq[3][4];
    {
        const uint4* bp = (const uint4*)Bpack;
        #pragma unroll
        for (int dx = 0; dx < 3; ++dx)
            #pragma unroll
            for (int nt = 0; nt < 4; ++nt) {
                uint4 t4 = bp[(dx * 4 + nt) * 64 + lane];
                bq[dx][nt] = *(short8v*)&t4;
            }
    }
    float Ac[4], Bc[4];
    #pragma unroll
    for (int nt = 0; nt < 4; ++nt) {
        Ac[nt] = Aarr[b * COUT + nt * 16 + i];
        Bc[nt] = B2arr[b * COUT + nt * 16 + i];
    }
    __syncthreads();

    for (int tp = 0; tp < 2; ++tp) {
        const int tg = 2 * wave + tp;           // col tile 16*tg
        f32x4 pm[4];
        #pragma unroll
        for (int nt = 0; nt < 4; ++nt) pm[nt] = (f32x4){-1e30f, -1e30f, -1e30f, -1e30f};

        #pragma unroll
        for (int p = 0; p < 2; ++p) {           // conv-row pairs {0,1},{2,3}
            f32x4 acc[2][4];
            #pragma unroll
            for (int rr = 0; rr < 2; ++rr)
                #pragma unroll
                for (int nt = 0; nt < 4; ++nt) acc[rr][nt] = (f32x4){0.f, 0.f, 0.f, 0.f};
            #pragma unroll
            for (int rr = 0; rr < 2; ++rr) {
                const int r = 2 * p + rr;
                #pragma unroll
                for (int dx = 0; dx < 3; ++dx) {
                    short8v a = *(const short8v*)&Abuf[r + g][16 * tg + i + dx][0];
                    #pragma unroll
                    for (int nt = 0; nt < 4; ++nt)
                        acc[rr][nt] = __builtin_amdgcn_mfma_f32_16x16x32_bf16(a, bq[dx][nt], acc[rr][nt], 0, 0, 0);
                }
            }
            #pragma unroll
            for (int nt = 0; nt < 4; ++nt)
                #pragma unroll
                for (int k = 0; k < 4; ++k) {
                    float e0 = fmaf(acc[0][nt][k], Ac[nt], Bc[nt]);
                    float e1 = fmaf(acc[1][nt][k], Ac[nt], Bc[nt]);
                    pm[nt][k] = fmaxf(pm[nt][k], fmaxf(e0, e1));
                }
        }
        const int pc = 4 * tg + g;
        if (pc < PH) {
            #pragma unroll
            for (int nt = 0; nt < 4; ++nt) {
                float m = fmaxf(fmaxf(pm[nt][0], pm[nt][1]), fmaxf(pm[nt][2], pm[nt][3]));
                m = fminf(fmaxf(m, 0.f), 1.f);
                out[((size_t)(b * COUT + nt * 16 + i) * PH + prow) * PH + pc] = m;
            }
        }
    }
}

extern "C" void kernel_launch(void* const* d_in, const int* in_sizes, int n_in,
                              void* d_out, int out_size, void* d_ws, size_t ws_size,
                              hipStream_t stream)
{
    const float* x   = (const float*)d_in[0];
    const float* w   = (const float*)d_in[1];
    const float* cbv = (const float*)d_in[2];
    const float* gnw = (const float*)d_in[3];
    const float* gnb = (const float*)d_in[4];
    const float* sc  = (const float*)d_in[5];
    float* out = (float*)d_out;

    float* part  = (float*)d_ws;                                  // 128*16*64*2 = 262144 f32 (1 MB)
    float* Aarr  = part + (size_t)BATCH * STRIPS_A * COUT * 2;    // 8192 f32
    float* B2arr = Aarr + BATCH * COUT;                           // 8192 f32
    short* Bpack = (short*)(B2arr + BATCH * COUT);                // 6144 bf16

    prep_weights<<<dim3(1), 256, 0, stream>>>(w, Bpack);
    conv_stats<<<dim3(STRIPS_A, BATCH), 256, 0, stream>>>(x, Bpack, part);
    finalize_stats<<<dim3(32), 256, 0, stream>>>(part, gnw, gnb, sc, cbv, Aarr, B2arr);
    conv_pool<<<dim3(PH, BATCH), 256, 0, stream>>>(x, Bpack, Aarr, B2arr, out);
}